// Round 12
// baseline (2215.295 us; speedup 1.0000x reference)
//
#include <hip/hip_runtime.h>
#include <math.h>

// ================= ROUND 12: DUAL DIAGNOSTIC =================
// Both kernels run NPASS=8 passes over their steady-state loop via a
// NON-unrolled outer loop (code size & inner structure identical to
// production; acc indices stay compile-time). Output scaled 0.125 (exact).
// Purpose: both dispatches exceed the ~45us harness-fill top-5 cutoff with
// full counters. Timing regresses this round by design.
// =============================================================

constexpr int BATCH = 64;
constexpr int IN    = 1024;
constexpr int NN    = 2048;
constexpr int OUTF  = 1024;

constexpr float INV2PI = 0.15915494309189535f;
constexpr float SQRT2  = 1.4142135623730951f;

constexpr int NPASS1 = 8;   // k_interf passes
constexpr int NPASS2 = 8;   // k_proj passes

template<int M>
__device__ __forceinline__ void butterfly(float* acc, int lane) {
    const bool hi = (lane & M) != 0;
#pragma unroll
    for (int j = 0; j < M; ++j) {
        const float send = hi ? acc[j] : acc[j + M];
        const float recv = __shfl_xor(send, M, 64);
        acc[j] = (hi ? acc[j + M] : acc[j]) + recv;
    }
    if constexpr (M > 1) butterfly<M / 2>(acc, lane);
}

// ---------------- Stage 1: interference (x NPASS1) ----------------
__global__ __launch_bounds__(512)
__attribute__((amdgpu_waves_per_eu(4, 4)))
void k_interf(const float* __restrict__ x, const float* __restrict__ W,
              const float* __restrict__ B, float* __restrict__ part) {
    __shared__ float xs[2][32 * 256];

    const int tid  = threadIdx.x;
    const int lane = tid & 63;
    const int wv   = __builtin_amdgcn_readfirstlane(tid >> 6);
    const int bid  = blockIdx.x;      // 512 blocks
    const int h    = bid & 1;
    const int n    = (bid >> 1) * 8 + wv;

    float4 iv2[4], bs2[4];
#pragma unroll
    for (int kc = 0; kc < 4; ++kc) {
        const float4 w4 = *(const float4*)&W[(size_t)n * IN + kc * 256 + 4 * lane];
        const float4 b4 = *(const float4*)&B[(size_t)n * IN + kc * 256 + 4 * lane];
        iv2[kc].x = INV2PI * __builtin_amdgcn_rcpf(1.0f + fabsf(w4.x));
        iv2[kc].y = INV2PI * __builtin_amdgcn_rcpf(1.0f + fabsf(w4.y));
        iv2[kc].z = INV2PI * __builtin_amdgcn_rcpf(1.0f + fabsf(w4.z));
        iv2[kc].w = INV2PI * __builtin_amdgcn_rcpf(1.0f + fabsf(w4.w));
        bs2[kc].x = fmaf(b4.x, INV2PI, 0.125f);
        bs2[kc].y = fmaf(b4.y, INV2PI, 0.125f);
        bs2[kc].z = fmaf(b4.z, INV2PI, 0.125f);
        bs2[kc].w = fmaf(b4.w, INV2PI, 0.125f);
    }

    const float* gx = x + (size_t)(h * 32) * IN;

#define STAGE(KC, P)                                                           \
    {                                                                          \
        _Pragma("unroll")                                                      \
        for (int rr = 0; rr < 4; ++rr) {                                       \
            const int r = wv * 4 + rr;                                         \
            __builtin_amdgcn_global_load_lds(                                  \
                (const __attribute__((address_space(1))) unsigned int*)        \
                    (gx + (size_t)r * IN + (KC) * 256 + 4 * lane),             \
                (__attribute__((address_space(3))) unsigned int*)              \
                    &xs[(P)][r * 256],                                         \
                16, 0, 0);                                                     \
        }                                                                      \
    }

    float acc[32];
#pragma unroll
    for (int j = 0; j < 32; ++j) acc[j] = 0.0f;

    STAGE(0, 0);
    __syncthreads();

#pragma unroll 1   // DIAG outer pass loop: NOT unrolled (keeps code size = prod)
    for (int pass = 0; pass < NPASS1; ++pass) {
#pragma unroll     // inner: full unroll, constant acc indices (no scratch)
        for (int kc = 0; kc < 4; ++kc) {
            const int p = kc & 1;   // 4 chunks/pass (even) -> parity pass-invariant
            if (kc < 3 || pass + 1 < NPASS1) STAGE((kc + 1) & 3, 1 - p);

            const float4 iv = iv2[kc], bs = bs2[kc];
#pragma unroll
            for (int bb = 0; bb < 32; ++bb) {
                const float4 xv = *(const float4*)&xs[p][bb * 256 + 4 * lane];
                const float a0 = fmaf(xv.x, iv.x, bs.x);
                const float a1 = fmaf(xv.y, iv.y, bs.y);
                const float a2 = fmaf(xv.z, iv.z, bs.z);
                const float a3 = fmaf(xv.w, iv.w, bs.w);
                const float t0 = __builtin_amdgcn_sinf(a0);
                const float t1 = __builtin_amdgcn_sinf(a1);
                const float t2 = __builtin_amdgcn_sinf(a2);
                const float t3 = __builtin_amdgcn_sinf(a3);
                acc[bb] += (t0 + t1) + (t2 + t3);
            }
            __syncthreads();
        }
    }
#undef STAGE

#pragma unroll
    for (int j = 0; j < 32; ++j) acc[j] += __shfl_xor(acc[j], 32, 64);
    butterfly<16>(acc, lane);

    if (lane < 32)   // acc = NPASS1 x sum -> scale by SQRT2/8 (exact)
        part[(size_t)(h * 32 + lane) * NN + n] = acc[0] * (SQRT2 * 0.125f);
}

// ---------------- Stage 2: projection (x NPASS2) ----------------
// R11 form: 4o x 4b float4, <=128 VGPR (no spill), 1024 blocks.
__global__ __launch_bounds__(256)
__attribute__((amdgpu_waves_per_eu(4, 4)))
void k_proj(const float* __restrict__ part, const float* __restrict__ ow,
            float* __restrict__ out) {
    const int tid  = threadIdx.x;
    const int lane = tid & 63;
    const int wv   = __builtin_amdgcn_readfirstlane(tid >> 6);
    const int bid  = blockIdx.x;              // 1024 blocks
    const int g    = bid & 7;
    const int inr  = bid >> 3;
    const int o0   = g * 128 + (inr & 31) * 4;
    const int b0   = ((inr >> 5) * 4 + wv) * 4;

    float4 acc[4][4];
#pragma unroll
    for (int o = 0; o < 4; ++o)
#pragma unroll
        for (int b = 0; b < 4; ++b) acc[o][b] = make_float4(0.f, 0.f, 0.f, 0.f);

#pragma unroll 1   // DIAG outer pass loop
    for (int pass = 0; pass < NPASS2; ++pass) {
#pragma unroll 2
        for (int it = 0; it < NN / 256; ++it) {
            const int nb = it * 256 + lane * 4;
            float4 wrow[4], vrow[4];
#pragma unroll
            for (int o = 0; o < 4; ++o)
                wrow[o] = *(const float4*)&ow[(size_t)(o0 + o) * NN + nb];
#pragma unroll
            for (int b = 0; b < 4; ++b)
                vrow[b] = *(const float4*)&part[(size_t)(b0 + b) * NN + nb];
#pragma unroll
            for (int o = 0; o < 4; ++o)
#pragma unroll
                for (int b = 0; b < 4; ++b) {
                    acc[o][b].x = fmaf(wrow[o].x, vrow[b].x, acc[o][b].x);
                    acc[o][b].y = fmaf(wrow[o].y, vrow[b].y, acc[o][b].y);
                    acc[o][b].z = fmaf(wrow[o].z, vrow[b].z, acc[o][b].z);
                    acc[o][b].w = fmaf(wrow[o].w, vrow[b].w, acc[o][b].w);
                }
        }
    }

    float accs[16];
#pragma unroll
    for (int o = 0; o < 4; ++o)
#pragma unroll
        for (int b = 0; b < 4; ++b)
            accs[o * 4 + b] =
                ((acc[o][b].x + acc[o][b].y) + (acc[o][b].z + acc[o][b].w)) * 0.125f;

#pragma unroll
    for (int j = 0; j < 16; ++j) accs[j] += __shfl_xor(accs[j], 32, 64);
#pragma unroll
    for (int j = 0; j < 16; ++j) accs[j] += __shfl_xor(accs[j], 16, 64);
    butterfly<8>(accs, lane);

    if (lane < 16)
        out[(size_t)(b0 + (lane & 3)) * OUTF + o0 + (lane >> 2)] = accs[0];
}

extern "C" void kernel_launch(void* const* d_in, const int* in_sizes, int n_in,
                              void* d_out, int out_size, void* d_ws, size_t ws_size,
                              hipStream_t stream) {
    const float* x  = (const float*)d_in[0];
    const float* W  = (const float*)d_in[1];
    const float* B  = (const float*)d_in[2];
    const float* ow = (const float*)d_in[3];
    float* out  = (float*)d_out;
    float* part = (float*)d_ws;    // 512 KB, [b][n] transposed

    k_interf<<<dim3(512), dim3(512), 0, stream>>>(x, W, B, part);
    k_proj  <<<dim3(1024), dim3(256), 0, stream>>>(part, ow, out);
}